// Round 16
// baseline (161.181 us; speedup 1.0000x reference)
//
#include <hip/hip_runtime.h>
#include <math.h>
#include <stdint.h>

#define N_EMBED   2048
#define N_EXPERTS 64
#define TOP_K     8
#define NT        64            // tokens per block (pass 1a)
#define KC        128           // k-chunk (pass 1a, fp32)
#define NCH       (N_EMBED / KC)
#define THR       4e-4f         // 3x the rigorous fp32 split-chain error bound (~1.3e-4)
#define XLD       130           // row stride (b64-aligned, proven round 13/15)

// ---------- fp64 monotone key (proven rounds 2-15) ----------
__device__ __forceinline__ uint64_t mono_key(double v, int lane) {
    uint64_t u = (uint64_t)__double_as_longlong(v);
    u = (u >> 63) ? ~u : (u | 0x8000000000000000ULL);
    return (u & ~63ULL) | (uint64_t)(63 - lane);
}
__device__ __forceinline__ double key_val(uint64_t k) {
    uint64_t u = k & ~63ULL;
    u = (u >> 63) ? (u & 0x7FFFFFFFFFFFFFFFULL) : ~u;
    return __longlong_as_double((long long)u);
}
// ---------- fp32 monotone key ----------
__device__ __forceinline__ uint32_t mono32(float v) {
    uint32_t u = __float_as_uint(v);
    return (u >> 31) ? ~u : (u | 0x80000000u);
}
__device__ __forceinline__ float val32(uint32_t k) {
    uint32_t u = (k & 0x80000000u) ? (k & 0x7FFFFFFFu) : ~k;
    return __uint_as_float(u);
}

// exact fp64 top-8 + softmax + store for one token (whole wave participates)
__device__ __forceinline__ void topk8_write(double v, int lane, size_t gtok,
                                            float* __restrict__ out_router,
                                            float* __restrict__ out_idx) {
    uint64_t mykey = mono_key(v, lane);
    float pv[TOP_K]; int pi[TOP_K];
    double vtop0 = 0.0;
#pragma unroll
    for (int j = 0; j < TOP_K; ++j) {
        uint64_t k = mykey;
#pragma unroll
        for (int m = 32; m >= 1; m >>= 1) {
            uint64_t o = (uint64_t)__shfl_xor((unsigned long long)k, m);
            k = (o > k) ? o : k;
        }
        const int widx = 63 - (int)(k & 63);
        const double wv = key_val(k);
        if (j == 0) vtop0 = wv;
        pv[j] = __expf((float)(wv - vtop0));
        pi[j] = widx;
        if (lane == widx) mykey = 0;
    }
    float s = 0.f;
#pragma unroll
    for (int j = 0; j < TOP_K; ++j) s += pv[j];
    const float inv = 1.f / s;

    float r = 0.f;
#pragma unroll
    for (int j = 0; j < TOP_K; ++j) r = (lane == pi[j]) ? pv[j] * inv : r;
    out_router[gtok * N_EXPERTS + lane] = r;

    float iv = 0.f;
#pragma unroll
    for (int j = 0; j < TOP_K; ++j) iv = (lane == j) ? (float)pi[j] : iv;
    if (lane < TOP_K)
        out_idx[gtok * TOP_K + lane] = iv;
}

// ---- prep: Wp fp64 k-major pairs (pass2) + Wg4 fp32 [e/4][k][4] (pass1a) ----
__global__ void combine_w_kernel(const float* __restrict__ Wl,
                                 const float* __restrict__ Wn,
                                 double* __restrict__ Wp,
                                 float* __restrict__ Wg4) {
    int f = blockIdx.x * 256 + threadIdx.x;    // = e*2048 + k, row-major
    int k = f & (N_EMBED - 1);
    int e = f >> 11;
    double w = (double)Wl[f] + (double)Wn[f];
    Wp[(((size_t)(k >> 1) << 6) + e) * 2 + (k & 1)] = w;
    Wg4[(((size_t)(e >> 2) * N_EMBED + k) << 2) + (e & 3)] = (float)w;
}

// ---- pass 1a: fp32 logits, 512 blocks = 256 token-grps x 2 expert-halves ----
#define XSI(t, k) xsf[(t) * XLD + (k)]

__global__ __launch_bounds__(1024, 1)
void pass1a_kernel(const float* __restrict__ x, const float* __restrict__ Wg4,
                   const float* __restrict__ bl, const float* __restrict__ bn,
                   float* __restrict__ nzg, int n_tokens) {
    __shared__ float xsf[64 * XLD];        // 33,280 B; reused for partials+nz

    const int tid  = threadIdx.x;
    const int lane = tid & 63;             // token (compute phase)
    const int wave = tid >> 6;             // 0..15
    const int tg   = blockIdx.x >> 1;
    const int eh   = blockIdx.x & 1;       // expert half: [32*eh, 32*eh+32)
    const int t0   = tg * NT;

    const int wid_u = __builtin_amdgcn_readfirstlane(wave);
    const int eg    = wid_u & 7;           // 4-expert group within the half
    const int h     = wid_u >> 3;          // K-half of each chunk
    const int hb    = h * 64;

    // staging: 16 threads per token, 8 consecutive k each
    const int stok = tid >> 4;
    const int sks  = (tid & 15) * 8;

    float accA[4], accB[4];
#pragma unroll
    for (int e = 0; e < 4; ++e) { accA[e] = 0.f; accB[e] = 0.f; }

    // prologue: prefetch chunk 0 into registers
    float4 pf0, pf1;
    {
        const float* xp = x + (size_t)(t0 + stok) * N_EMBED + sks;
        pf0 = *reinterpret_cast<const float4*>(xp);
        pf1 = *reinterpret_cast<const float4*>(xp + 4);
    }

    for (int c = 0; c < NCH; ++c) {
        __syncthreads();               // all waves done reading xsf (prev chunk)

        // commit prefetched regs -> LDS
        {
            float2 w0, w1, w2, w3;
            w0.x = pf0.x; w0.y = pf0.y; w1.x = pf0.z; w1.y = pf0.w;
            w2.x = pf1.x; w2.y = pf1.y; w3.x = pf1.z; w3.y = pf1.w;
            *reinterpret_cast<float2*>(&XSI(stok, sks + 0)) = w0;
            *reinterpret_cast<float2*>(&XSI(stok, sks + 2)) = w1;
            *reinterpret_cast<float2*>(&XSI(stok, sks + 4)) = w2;
            *reinterpret_cast<float2*>(&XSI(stok, sks + 6)) = w3;
        }
        __syncthreads();               // chunk staged

        // issue next chunk's global loads (land during compute)
        if (c + 1 < NCH) {
            const float* xp = x + (size_t)(t0 + stok) * N_EMBED + (c + 1) * KC + sks;
            pf0 = *reinterpret_cast<const float4*>(xp);
            pf1 = *reinterpret_cast<const float4*>(xp + 4);
        }

        // compute: per 2k: 1 ds_read_b64 + 8 scalar W floats + 8 fma (4 experts)
        const float* wb = Wg4 + ((size_t)(eh * 8 + eg) * N_EMBED
                                 + (size_t)c * KC + hb) * 4;
#pragma unroll 4
        for (int i2 = 0; i2 < 16; ++i2) {
            const float2 xA = *reinterpret_cast<const float2*>(&XSI(lane, hb + 4 * i2));
            const float2 xB = *reinterpret_cast<const float2*>(&XSI(lane, hb + 4 * i2 + 2));
            const float* wA = wb + 16 * i2;
#pragma unroll
            for (int e = 0; e < 4; ++e) accA[e] = fmaf(xA.x, wA[e], accA[e]);
#pragma unroll
            for (int e = 0; e < 4; ++e) accA[e] = fmaf(xA.y, wA[4 + e], accA[e]);
#pragma unroll
            for (int e = 0; e < 4; ++e) accB[e] = fmaf(xB.x, wA[8 + e], accB[e]);
#pragma unroll
            for (int e = 0; e < 4; ++e) accB[e] = fmaf(xB.y, wA[12 + e], accB[e]);
        }
    }
    __syncthreads();                   // done with x buffer; reuse for partials

    // ---- combine K-halves + bias -> nz_lds[token][expert-local] ----
    float* part   = xsf;                     // part[(eg*64+t)*4 + e] : 2048 floats
    float* nz_lds = xsf + 2048;              // nz[t*33 + el]         : 2112 floats

    if (h == 1) {
#pragma unroll
        for (int e = 0; e < 4; ++e)
            part[(eg * 64 + lane) * 4 + e] = accA[e] + accB[e];
    }
    __syncthreads();
    if (h == 0) {
#pragma unroll
        for (int e = 0; e < 4; ++e) {
            const int el = eg * 4 + e;               // 0..31 within half
            const int ex = eh * 32 + el;             // global expert
            const float be = (float)((double)bl[ex] + (double)bn[ex]);
            nz_lds[lane * 33 + el] =
                (accA[e] + accB[e]) + part[(eg * 64 + lane) * 4 + e] + be;
        }
    }
    __syncthreads();

    // ---- coalesced write LDS -> nzg[token][64] (our 32-expert half) ----
    {
        const int tok = tid >> 4;                    // 0..63
        const int cl  = (tid & 15) * 2;              // 0..30 step 2
        float2 v;
        v.x = nz_lds[tok * 33 + cl];
        v.y = nz_lds[tok * 33 + cl + 1];
        *reinterpret_cast<float2*>(&nzg[(size_t)(t0 + tok) * N_EXPERTS
                                        + eh * 32 + cl]) = v;
    }
}

// ---- pass 1b: top-9 screen + flag + softmax + stores (epilogue, verbatim) ----
__global__ __launch_bounds__(1024, 1)
void pass1b_kernel(const float* __restrict__ nzg, float* __restrict__ out,
                   uint32_t* __restrict__ flags, int n_tokens) {
    const int tid  = threadIdx.x;
    const int lane = tid & 63;             // expert
    const int wave = tid >> 6;             // 0..15
    const int t0   = blockIdx.x * 64;
    const int tb   = wave * 4;

    float* out_router = out;
    float* out_idx    = out + (size_t)n_tokens * N_EXPERTS;

#pragma unroll
    for (int t = 0; t < 4; ++t) {
        const float v = nzg[(size_t)(t0 + tb + t) * N_EXPERTS + lane];
        uint32_t mykey = (mono32(v) & ~63u) | (uint32_t)(63 - lane);

        float pv[TOP_K]; int pi[TOP_K];
        float vtop = 0.f, vprev = 0.f, ming = 1e30f;
#pragma unroll
        for (int j = 0; j < 9; ++j) {
            uint32_t k = mykey;
#pragma unroll
            for (int m = 32; m >= 1; m >>= 1) {
                uint32_t o = (uint32_t)__shfl_xor((int)k, m);
                k = (o > k) ? o : k;
            }
            const int widx = 63 - (int)(k & 63);
            const float wv = val32(k);
            if (j == 0) vtop = wv;
            if (j > 0) ming = fminf(ming, vprev - wv);
            vprev = wv;
            if (j < TOP_K) {
                pv[j] = __expf(wv - vtop);
                pi[j] = widx;
                if (lane == widx) mykey = 0;            // remove winner
            }
        }
        float s = 0.f;
#pragma unroll
        for (int j = 0; j < TOP_K; ++j) s += pv[j];
        const float inv = 1.f / s;

        float r = 0.f;
#pragma unroll
        for (int j = 0; j < TOP_K; ++j) r = (lane == pi[j]) ? pv[j] * inv : r;
        out_router[(size_t)(t0 + tb + t) * N_EXPERTS + lane] = r;

        float iv = 0.f;
#pragma unroll
        for (int j = 0; j < TOP_K; ++j) iv = (lane == j) ? (float)pi[j] : iv;
        if (lane < TOP_K)
            out_idx[(size_t)(t0 + tb + t) * TOP_K + lane] = iv;

        if (lane == 0)
            flags[t0 + tb + t] = (ming < THR) ? 1u : 0u;
    }
}

// ---- pass 2: exact fp64 repair, block per token, coalesced k-major W
//      (VERBATIM rounds 13/15) ----
__global__ __launch_bounds__(256, 4)
void pass2_kernel(const float* __restrict__ x, const double* __restrict__ Wp,
                  const float* __restrict__ bl, const float* __restrict__ bn,
                  const uint32_t* __restrict__ flags,
                  float* __restrict__ out, int n_tokens) {
    __shared__ float  xls[N_EMBED];          // 8 KB x row
    __shared__ double dpart[4][N_EXPERTS];   // 2 KB partials

    const int tid  = threadIdx.x;
    const int lane = tid & 63;               // expert
    const int wave = tid >> 6;               // 0..3 (k-quarter)
    const int t    = blockIdx.x;

    if (flags[t] == 0) return;               // block-uniform fast exit

    {
        const float* xr = x + ((size_t)t << 11) + tid * 8;
        const float4 a = *reinterpret_cast<const float4*>(xr);
        const float4 b = *reinterpret_cast<const float4*>(xr + 4);
        *reinterpret_cast<float4*>(&xls[tid * 8])     = a;
        *reinterpret_cast<float4*>(&xls[tid * 8 + 4]) = b;
    }
    __syncthreads();

    double acc = 0.0;
    const double* wq = Wp + (((size_t)wave << 8) * 64 + lane) * 2;
#pragma unroll 4
    for (int i = 0; i < 256; ++i) {
        const float2  xf = *reinterpret_cast<const float2*>(&xls[(wave << 9) + 2 * i]);
        const double2 wp = *reinterpret_cast<const double2*>(wq + (size_t)i * 128);
        acc = fma((double)xf.x, wp.x, acc);
        acc = fma((double)xf.y, wp.y, acc);
    }
    dpart[wave][lane] = acc;
    __syncthreads();

    if (wave == 0) {
        const double myb = (double)bl[lane] + (double)bn[lane];
        double v = myb + dpart[0][lane] + dpart[1][lane] + dpart[2][lane] + dpart[3][lane];
        float* out_router = out;
        float* out_idx    = out + (size_t)n_tokens * N_EXPERTS;
        topk8_write(v, lane, (size_t)t, out_router, out_idx);
    }
}

// ---- fallback: proven round-6 kernel (used only if ws too small) ----
__global__ __launch_bounds__(512, 4)
void noisy_topk_fallback(const float* __restrict__ x,
                         const float* __restrict__ Wl, const float* __restrict__ bl,
                         const float* __restrict__ Wn, const float* __restrict__ bn,
                         float* __restrict__ out, int n_tokens) {
    __shared__ double Wt[64][N_EXPERTS];
    __shared__ double xsd[32][64];

    const int tid  = threadIdx.x;
    const int lane = tid & 63;
    const int wave = tid >> 6;
    const int t0   = blockIdx.x * 32;
    const int tb   = wave * 4;

    const int se = tid >> 3;
    const int sk = (tid & 7) * 8;
    const int st = tid >> 4;
    const int sx = (tid & 15) * 4;

    double acc[4];
#pragma unroll
    for (int t = 0; t < 4; ++t) acc[t] = 0.0;

    const double myb = (double)bl[lane] + (double)bn[lane];

    for (int c = 0; c < N_EMBED / 64; ++c) {
        const int kc = c * 64;
        __syncthreads();
        const float* wlp = Wl + (size_t)se * N_EMBED + kc + sk;
        const float* wnp = Wn + (size_t)se * N_EMBED + kc + sk;
#pragma unroll
        for (int i = 0; i < 2; ++i) {
            const float4 a = *reinterpret_cast<const float4*>(wlp + 4 * i);
            const float4 b = *reinterpret_cast<const float4*>(wnp + 4 * i);
            Wt[sk + 4 * i + 0][se] = (double)a.x + (double)b.x;
            Wt[sk + 4 * i + 1][se] = (double)a.y + (double)b.y;
            Wt[sk + 4 * i + 2][se] = (double)a.z + (double)b.z;
            Wt[sk + 4 * i + 3][se] = (double)a.w + (double)b.w;
        }
        {
            const float* xp = x + (size_t)(t0 + st) * N_EMBED + kc + sx;
            const float4 a = *reinterpret_cast<const float4*>(xp);
            xsd[st][sx + 0] = (double)a.x;
            xsd[st][sx + 1] = (double)a.y;
            xsd[st][sx + 2] = (double)a.z;
            xsd[st][sx + 3] = (double)a.w;
        }
        __syncthreads();
#pragma unroll 4
        for (int kk = 0; kk < 64; kk += 4) {
            const double w0 = Wt[kk + 0][lane];
            const double w1 = Wt[kk + 1][lane];
            const double w2 = Wt[kk + 2][lane];
            const double w3 = Wt[kk + 3][lane];
#pragma unroll
            for (int t = 0; t < 4; ++t) {
                const double2 p = *reinterpret_cast<const double2*>(&xsd[tb + t][kk]);
                const double2 q = *reinterpret_cast<const double2*>(&xsd[tb + t][kk + 2]);
                acc[t] = fma(p.x, w0, acc[t]);
                acc[t] = fma(p.y, w1, acc[t]);
                acc[t] = fma(q.x, w2, acc[t]);
                acc[t] = fma(q.y, w3, acc[t]);
            }
        }
    }

    float* out_router = out;
    float* out_idx    = out + (size_t)n_tokens * N_EXPERTS;
#pragma unroll
    for (int t = 0; t < 4; ++t)
        topk8_write(acc[t] + myb, lane, (size_t)(t0 + tb + t), out_router, out_idx);
}

extern "C" void kernel_launch(void* const* d_in, const int* in_sizes, int n_in,
                              void* d_out, int out_size, void* d_ws, size_t ws_size,
                              hipStream_t stream) {
    const float* x  = (const float*)d_in[0];
    const float* Wl = (const float*)d_in[1];
    const float* bl = (const float*)d_in[2];
    const float* Wn = (const float*)d_in[3];
    const float* bn = (const float*)d_in[4];
    float* out = (float*)d_out;

    int n_tokens = in_sizes[0] / N_EMBED;              // 16384

    const size_t off_wg4   = (size_t)N_EXPERTS * N_EMBED * sizeof(double);   // 1 MB
    const size_t off_nzg   = off_wg4 + (size_t)N_EXPERTS * N_EMBED * sizeof(float);
    const size_t off_flags = off_nzg + (size_t)n_tokens * N_EXPERTS * sizeof(float);
    const size_t need      = off_flags + (size_t)n_tokens * sizeof(uint32_t);

    if (ws_size >= need) {
        double*   Wp    = (double*)d_ws;
        float*    Wg4   = (float*)((char*)d_ws + off_wg4);
        float*    nzg   = (float*)((char*)d_ws + off_nzg);
        uint32_t* flags = (uint32_t*)((char*)d_ws + off_flags);

        hipLaunchKernelGGL(combine_w_kernel, dim3((N_EXPERTS * N_EMBED) / 256),
                           dim3(256), 0, stream, Wl, Wn, Wp, Wg4);
        hipLaunchKernelGGL(pass1a_kernel, dim3((n_tokens / NT) * 2), dim3(1024),
                           0, stream, x, Wg4, bl, bn, nzg, n_tokens);
        hipLaunchKernelGGL(pass1b_kernel, dim3(n_tokens / 64), dim3(1024),
                           0, stream, nzg, out, flags, n_tokens);
        hipLaunchKernelGGL(pass2_kernel, dim3(n_tokens), dim3(256), 0, stream,
                           x, Wp, bl, bn, flags, out, n_tokens);
    } else {
        hipLaunchKernelGGL(noisy_topk_fallback, dim3(n_tokens / 32), dim3(512), 0, stream,
                           x, Wl, bl, Wn, bn, out, n_tokens);
    }
}

// Round 17
// 126.035 us; speedup vs baseline: 1.2789x; 1.2789x over previous
//
#include <hip/hip_runtime.h>
#include <math.h>
#include <stdint.h>

#define N_EMBED   2048
#define N_EXPERTS 64
#define TOP_K     8
#define THR       4e-4f         // 3x rigorous fp32 split-chain error bound
#define P1_KQ     8             // K split factor (pass 1a)
#define P1_KB     (N_EMBED / P1_KQ)   // 256 k per block
#define P1_KC     64            // k-chunk staged in LDS
#define P1_NCH    (P1_KB / P1_KC)     // 4
#define SLD       66            // x tile row stride (floats): b64-aligned, 2-way banks

// ---------- fp64 monotone key (proven rounds 2-16) ----------
__device__ __forceinline__ uint64_t mono_key(double v, int lane) {
    uint64_t u = (uint64_t)__double_as_longlong(v);
    u = (u >> 63) ? ~u : (u | 0x8000000000000000ULL);
    return (u & ~63ULL) | (uint64_t)(63 - lane);
}
__device__ __forceinline__ double key_val(uint64_t k) {
    uint64_t u = k & ~63ULL;
    u = (u >> 63) ? (u & 0x7FFFFFFFFFFFFFFFULL) : ~u;
    return __longlong_as_double((long long)u);
}
// ---------- fp32 monotone key ----------
__device__ __forceinline__ uint32_t mono32(float v) {
    uint32_t u = __float_as_uint(v);
    return (u >> 31) ? ~u : (u | 0x80000000u);
}
__device__ __forceinline__ float val32(uint32_t k) {
    uint32_t u = (k & 0x80000000u) ? (k & 0x7FFFFFFFu) : ~k;
    return __uint_as_float(u);
}

// exact fp64 top-8 + softmax + store for one token (whole wave participates)
__device__ __forceinline__ void topk8_write(double v, int lane, size_t gtok,
                                            float* __restrict__ out_router,
                                            float* __restrict__ out_idx) {
    uint64_t mykey = mono_key(v, lane);
    float pv[TOP_K]; int pi[TOP_K];
    double vtop0 = 0.0;
#pragma unroll
    for (int j = 0; j < TOP_K; ++j) {
        uint64_t k = mykey;
#pragma unroll
        for (int m = 32; m >= 1; m >>= 1) {
            uint64_t o = (uint64_t)__shfl_xor((unsigned long long)k, m);
            k = (o > k) ? o : k;
        }
        const int widx = 63 - (int)(k & 63);
        const double wv = key_val(k);
        if (j == 0) vtop0 = wv;
        pv[j] = __expf((float)(wv - vtop0));
        pi[j] = widx;
        if (lane == widx) mykey = 0;
    }
    float s = 0.f;
#pragma unroll
    for (int j = 0; j < TOP_K; ++j) s += pv[j];
    const float inv = 1.f / s;

    float r = 0.f;
#pragma unroll
    for (int j = 0; j < TOP_K; ++j) r = (lane == pi[j]) ? pv[j] * inv : r;
    out_router[gtok * N_EXPERTS + lane] = r;

    float iv = 0.f;
#pragma unroll
    for (int j = 0; j < TOP_K; ++j) iv = (lane == j) ? (float)pi[j] : iv;
    if (lane < TOP_K)
        out_idx[gtok * TOP_K + lane] = iv;
}

// ---- prep: Wp fp64 k-major pairs (pass2) + Wgf fp32 [eg][k][8] (pass1) ----
__global__ void combine_w_kernel(const float* __restrict__ Wl,
                                 const float* __restrict__ Wn,
                                 double* __restrict__ Wp,
                                 float* __restrict__ Wgf) {
    int f = blockIdx.x * 256 + threadIdx.x;    // = e*2048 + k, row-major
    int k = f & (N_EMBED - 1);
    int e = f >> 11;
    double w = (double)Wl[f] + (double)Wn[f];
    Wp[(((size_t)(k >> 1) << 6) + e) * 2 + (k & 1)] = w;
    Wgf[(((size_t)(e >> 3) * N_EMBED + k) << 3) + (e & 7)] = (float)w;
}

// ---- pass 1a: fp32 GEMM partials. 2048 blocks = 256 tg x 8 kq.
//      512 thr = 8 waves = 8 expert-groups; 4 blocks/CU -> 32 waves/CU ----
__global__ __launch_bounds__(512, 8)
void pass1a_kernel(const float* __restrict__ x, const float* __restrict__ Wgf,
                   float* __restrict__ part, int n_tokens) {
    __shared__ float xsf[64 * SLD];        // 16,896 B; reused as nz_lds[64][65]

    const int tid  = threadIdx.x;
    const int lane = tid & 63;             // token
    const int wave = tid >> 6;             // 0..7 = expert group
    const int tg   = blockIdx.x >> 3;
    const int kq   = blockIdx.x & 7;
    const int t0   = tg * 64;
    const int k0   = kq * P1_KB;

    const int eg = __builtin_amdgcn_readfirstlane(wave);

    // staging: 8 threads per token, 8 consecutive k each
    const int stok = tid >> 3;
    const int sks  = (tid & 7) * 8;

    float accA[8], accB[8];
#pragma unroll
    for (int e = 0; e < 8; ++e) { accA[e] = 0.f; accB[e] = 0.f; }

    // prologue: prefetch chunk 0
    float4 pf0, pf1;
    {
        const float* xp = x + (size_t)(t0 + stok) * N_EMBED + k0 + sks;
        pf0 = *reinterpret_cast<const float4*>(xp);
        pf1 = *reinterpret_cast<const float4*>(xp + 4);
    }

    for (int c = 0; c < P1_NCH; ++c) {
        __syncthreads();               // previous chunk fully read

        // commit prefetched regs -> LDS
        {
            float* row = &xsf[stok * SLD + sks];
            float2 w0, w1, w2, w3;
            w0.x = pf0.x; w0.y = pf0.y; w1.x = pf0.z; w1.y = pf0.w;
            w2.x = pf1.x; w2.y = pf1.y; w3.x = pf1.z; w3.y = pf1.w;
            *reinterpret_cast<float2*>(row + 0) = w0;
            *reinterpret_cast<float2*>(row + 2) = w1;
            *reinterpret_cast<float2*>(row + 4) = w2;
            *reinterpret_cast<float2*>(row + 6) = w3;
        }
        __syncthreads();               // chunk staged

        // issue next chunk's loads (land during compute)
        if (c + 1 < P1_NCH) {
            const float* xp = x + (size_t)(t0 + stok) * N_EMBED + k0 + (c + 1) * P1_KC + sks;
            pf0 = *reinterpret_cast<const float4*>(xp);
            pf1 = *reinterpret_cast<const float4*>(xp + 4);
        }

        // compute: per 4k: 2 ds_read_b64 + 32 scalar W floats + 32 fma
        const float* wb = Wgf + ((size_t)eg * N_EMBED + k0 + c * P1_KC) * 8;
#pragma unroll 4
        for (int i = 0; i < 16; ++i) {
            const float2 xA = *reinterpret_cast<const float2*>(&xsf[lane * SLD + 4 * i]);
            const float2 xB = *reinterpret_cast<const float2*>(&xsf[lane * SLD + 4 * i + 2]);
            const float* w = wb + 32 * i;
#pragma unroll
            for (int e = 0; e < 8; ++e) accA[e] = fmaf(xA.x, w[e], accA[e]);
#pragma unroll
            for (int e = 0; e < 8; ++e) accA[e] = fmaf(xA.y, w[8 + e], accA[e]);
#pragma unroll
            for (int e = 0; e < 8; ++e) accB[e] = fmaf(xB.x, w[16 + e], accB[e]);
#pragma unroll
            for (int e = 0; e < 8; ++e) accB[e] = fmaf(xB.y, w[24 + e], accB[e]);
        }
    }
    __syncthreads();                   // x tile dead; reuse as nz_lds

    // transpose partials through LDS for coalesced global write
    float* nz_lds = xsf;               // [64][65]
#pragma unroll
    for (int e = 0; e < 8; ++e)
        nz_lds[lane * 65 + eg * 8 + e] = accA[e] + accB[e];
    __syncthreads();

    {
        const int wt = tid >> 3;               // token 0..63
        const int wc = (tid & 7) * 8;          // expert col 0..56
        float4 v0, v1;
        v0.x = nz_lds[wt * 65 + wc + 0];
        v0.y = nz_lds[wt * 65 + wc + 1];
        v0.z = nz_lds[wt * 65 + wc + 2];
        v0.w = nz_lds[wt * 65 + wc + 3];
        v1.x = nz_lds[wt * 65 + wc + 4];
        v1.y = nz_lds[wt * 65 + wc + 5];
        v1.z = nz_lds[wt * 65 + wc + 6];
        v1.w = nz_lds[wt * 65 + wc + 7];
        float* dst = part + ((size_t)kq * n_tokens + t0 + wt) * N_EXPERTS + wc;
        *reinterpret_cast<float4*>(dst)     = v0;
        *reinterpret_cast<float4*>(dst + 4) = v1;
    }
}

// ---- pass 1b: sum 8 K-partials + bias, top-9 screen, flag, softmax, store ----
__global__ __launch_bounds__(1024, 1)
void pass1b_kernel(const float* __restrict__ part,
                   const float* __restrict__ bl, const float* __restrict__ bn,
                   float* __restrict__ out, uint32_t* __restrict__ flags,
                   int n_tokens) {
    const int tid  = threadIdx.x;
    const int lane = tid & 63;             // expert
    const int wave = tid >> 6;             // 0..15
    const int t0   = blockIdx.x * 64;
    const int tb   = wave * 4;

    const float be = (float)((double)bl[lane] + (double)bn[lane]);
    float* out_router = out;
    float* out_idx    = out + (size_t)n_tokens * N_EXPERTS;

#pragma unroll
    for (int t = 0; t < 4; ++t) {
        const float* pb = part + (size_t)(t0 + tb + t) * N_EXPERTS + lane;
        float v = 0.f;
#pragma unroll
        for (int kq = 0; kq < P1_KQ; ++kq)
            v += pb[(size_t)kq * n_tokens * N_EXPERTS];
        v += be;

        uint32_t mykey = (mono32(v) & ~63u) | (uint32_t)(63 - lane);

        float pv[TOP_K]; int pi[TOP_K];
        float vtop = 0.f, vprev = 0.f, ming = 1e30f;
#pragma unroll
        for (int j = 0; j < 9; ++j) {
            uint32_t k = mykey;
#pragma unroll
            for (int m = 32; m >= 1; m >>= 1) {
                uint32_t o = (uint32_t)__shfl_xor((int)k, m);
                k = (o > k) ? o : k;
            }
            const int widx = 63 - (int)(k & 63);
            const float wv = val32(k);
            if (j == 0) vtop = wv;
            if (j > 0) ming = fminf(ming, vprev - wv);
            vprev = wv;
            if (j < TOP_K) {
                pv[j] = __expf(wv - vtop);
                pi[j] = widx;
                if (lane == widx) mykey = 0;            // remove winner
            }
        }
        float s = 0.f;
#pragma unroll
        for (int j = 0; j < TOP_K; ++j) s += pv[j];
        const float inv = 1.f / s;

        float r = 0.f;
#pragma unroll
        for (int j = 0; j < TOP_K; ++j) r = (lane == pi[j]) ? pv[j] * inv : r;
        out_router[(size_t)(t0 + tb + t) * N_EXPERTS + lane] = r;

        float iv = 0.f;
#pragma unroll
        for (int j = 0; j < TOP_K; ++j) iv = (lane == j) ? (float)pi[j] : iv;
        if (lane < TOP_K)
            out_idx[(size_t)(t0 + tb + t) * TOP_K + lane] = iv;

        if (lane == 0)
            flags[t0 + tb + t] = (ming < THR) ? 1u : 0u;
    }
}

// ---- mid fallback: round-15 monolithic pass1 (proven, needs only 1.6 MB ws) ----
#define XLD 130
#define FSI(t, k) xsf[(t) * XLD + (k)]
__global__ __launch_bounds__(1024, 1)
void pass1_full_kernel(const float* __restrict__ x, const float* __restrict__ Wgf,
                       const float* __restrict__ bl, const float* __restrict__ bn,
                       float* __restrict__ out, uint32_t* __restrict__ flags,
                       int n_tokens) {
    __shared__ float xsf[64 * XLD];

    const int tid  = threadIdx.x;
    const int lane = tid & 63;
    const int wave = tid >> 6;
    const int t0   = blockIdx.x * 64;

    const int wid_u = __builtin_amdgcn_readfirstlane(wave);
    const int eg    = wid_u & 7;
    const int h     = wid_u >> 3;
    const int hb    = h * 64;

    const int stok = tid >> 4;
    const int sks  = (tid & 15) * 8;

    float accA[8], accB[8];
#pragma unroll
    for (int e = 0; e < 8; ++e) { accA[e] = 0.f; accB[e] = 0.f; }

    float4 pf0, pf1;
    {
        const float* xp = x + (size_t)(t0 + stok) * N_EMBED + sks;
        pf0 = *reinterpret_cast<const float4*>(xp);
        pf1 = *reinterpret_cast<const float4*>(xp + 4);
    }

    for (int c = 0; c < N_EMBED / 128; ++c) {
        __syncthreads();
        {
            float2 w0, w1, w2, w3;
            w0.x = pf0.x; w0.y = pf0.y; w1.x = pf0.z; w1.y = pf0.w;
            w2.x = pf1.x; w2.y = pf1.y; w3.x = pf1.z; w3.y = pf1.w;
            *reinterpret_cast<float2*>(&FSI(stok, sks + 0)) = w0;
            *reinterpret_cast<float2*>(&FSI(stok, sks + 2)) = w1;
            *reinterpret_cast<float2*>(&FSI(stok, sks + 4)) = w2;
            *reinterpret_cast<float2*>(&FSI(stok, sks + 6)) = w3;
        }
        __syncthreads();
        if (c + 1 < N_EMBED / 128) {
            const float* xp = x + (size_t)(t0 + stok) * N_EMBED + (c + 1) * 128 + sks;
            pf0 = *reinterpret_cast<const float4*>(xp);
            pf1 = *reinterpret_cast<const float4*>(xp + 4);
        }
        const float* wb = Wgf + ((size_t)eg * N_EMBED + (size_t)c * 128 + hb) * 8;
#pragma unroll 4
        for (int i2 = 0; i2 < 16; ++i2) {
            const float2 xA = *reinterpret_cast<const float2*>(&FSI(lane, hb + 4 * i2));
            const float2 xB = *reinterpret_cast<const float2*>(&FSI(lane, hb + 4 * i2 + 2));
            const float* wA = wb + 32 * i2;
            const float* wB = wb + 32 * i2 + 16;
#pragma unroll
            for (int e = 0; e < 8; ++e) accA[e] = fmaf(xA.x, wA[e], accA[e]);
#pragma unroll
            for (int e = 0; e < 8; ++e) accA[e] = fmaf(xA.y, wA[8 + e], accA[e]);
#pragma unroll
            for (int e = 0; e < 8; ++e) accB[e] = fmaf(xB.x, wB[e], accB[e]);
#pragma unroll
            for (int e = 0; e < 8; ++e) accB[e] = fmaf(xB.y, wB[8 + e], accB[e]);
        }
    }
    __syncthreads();

    float* nz   = xsf;
    float* partl = xsf + 4160;

    if (h == 1) {
#pragma unroll
        for (int e = 0; e < 8; ++e)
            partl[(eg * 64 + lane) * 8 + e] = accA[e] + accB[e];
    }
    __syncthreads();
    if (h == 0) {
#pragma unroll
        for (int e = 0; e < 8; ++e) {
            const int ex = eg * 8 + e;
            const float be = (float)((double)bl[ex] + (double)bn[ex]);
            nz[lane * 65 + ex] = (accA[e] + accB[e]) + partl[(eg * 64 + lane) * 8 + e] + be;
        }
    }
    __syncthreads();

    float* out_router = out;
    float* out_idx    = out + (size_t)n_tokens * N_EXPERTS;
    const int tb = wave * 4;

#pragma unroll
    for (int t = 0; t < 4; ++t) {
        const float v = nz[(tb + t) * 65 + lane];
        uint32_t mykey = (mono32(v) & ~63u) | (uint32_t)(63 - lane);

        float pv[TOP_K]; int pi[TOP_K];
        float vtop = 0.f, vprev = 0.f, ming = 1e30f;
#pragma unroll
        for (int j = 0; j < 9; ++j) {
            uint32_t k = mykey;
#pragma unroll
            for (int m = 32; m >= 1; m >>= 1) {
                uint32_t o = (uint32_t)__shfl_xor((int)k, m);
                k = (o > k) ? o : k;
            }
            const int widx = 63 - (int)(k & 63);
            const float wv = val32(k);
            if (j == 0) vtop = wv;
            if (j > 0) ming = fminf(ming, vprev - wv);
            vprev = wv;
            if (j < TOP_K) {
                pv[j] = __expf(wv - vtop);
                pi[j] = widx;
                if (lane == widx) mykey = 0;
            }
        }
        float s = 0.f;
#pragma unroll
        for (int j = 0; j < TOP_K; ++j) s += pv[j];
        const float inv = 1.f / s;

        float r = 0.f;
#pragma unroll
        for (int j = 0; j < TOP_K; ++j) r = (lane == pi[j]) ? pv[j] * inv : r;
        out_router[(size_t)(t0 + tb + t) * N_EXPERTS + lane] = r;

        float iv = 0.f;
#pragma unroll
        for (int j = 0; j < TOP_K; ++j) iv = (lane == j) ? (float)pi[j] : iv;
        if (lane < TOP_K)
            out_idx[(size_t)(t0 + tb + t) * TOP_K + lane] = iv;

        if (lane == 0)
            flags[t0 + tb + t] = (ming < THR) ? 1u : 0u;
    }
}

// ---- pass 2: exact fp64 repair, block per token (VERBATIM rounds 13/15) ----
__global__ __launch_bounds__(256, 4)
void pass2_kernel(const float* __restrict__ x, const double* __restrict__ Wp,
                  const float* __restrict__ bl, const float* __restrict__ bn,
                  const uint32_t* __restrict__ flags,
                  float* __restrict__ out, int n_tokens) {
    __shared__ float  xls[N_EMBED];
    __shared__ double dpart[4][N_EXPERTS];

    const int tid  = threadIdx.x;
    const int lane = tid & 63;
    const int wave = tid >> 6;
    const int t    = blockIdx.x;

    if (flags[t] == 0) return;

    {
        const float* xr = x + ((size_t)t << 11) + tid * 8;
        const float4 a = *reinterpret_cast<const float4*>(xr);
        const float4 b = *reinterpret_cast<const float4*>(xr + 4);
        *reinterpret_cast<float4*>(&xls[tid * 8])     = a;
        *reinterpret_cast<float4*>(&xls[tid * 8 + 4]) = b;
    }
    __syncthreads();

    double acc = 0.0;
    const double* wq = Wp + (((size_t)wave << 8) * 64 + lane) * 2;
#pragma unroll 4
    for (int i = 0; i < 256; ++i) {
        const float2  xf = *reinterpret_cast<const float2*>(&xls[(wave << 9) + 2 * i]);
        const double2 wp = *reinterpret_cast<const double2*>(wq + (size_t)i * 128);
        acc = fma((double)xf.x, wp.x, acc);
        acc = fma((double)xf.y, wp.y, acc);
    }
    dpart[wave][lane] = acc;
    __syncthreads();

    if (wave == 0) {
        const double myb = (double)bl[lane] + (double)bn[lane];
        double v = myb + dpart[0][lane] + dpart[1][lane] + dpart[2][lane] + dpart[3][lane];
        float* out_router = out;
        float* out_idx    = out + (size_t)n_tokens * N_EXPERTS;
        topk8_write(v, lane, (size_t)t, out_router, out_idx);
    }
}

// ---- ultimate fallback: proven round-6 kernel (no workspace needed) ----
__global__ __launch_bounds__(512, 4)
void noisy_topk_fallback(const float* __restrict__ x,
                         const float* __restrict__ Wl, const float* __restrict__ bl,
                         const float* __restrict__ Wn, const float* __restrict__ bn,
                         float* __restrict__ out, int n_tokens) {
    __shared__ double Wt[64][N_EXPERTS];
    __shared__ double xsd[32][64];

    const int tid  = threadIdx.x;
    const int lane = tid & 63;
    const int wave = tid >> 6;
    const int t0   = blockIdx.x * 32;
    const int tb   = wave * 4;

    const int se = tid >> 3;
    const int sk = (tid & 7) * 8;
    const int st = tid >> 4;
    const int sx = (tid & 15) * 4;

    double acc[4];
#pragma unroll
    for (int t = 0; t < 4; ++t) acc[t] = 0.0;

    const double myb = (double)bl[lane] + (double)bn[lane];

    for (int c = 0; c < N_EMBED / 64; ++c) {
        const int kc = c * 64;
        __syncthreads();
        const float* wlp = Wl + (size_t)se * N_EMBED + kc + sk;
        const float* wnp = Wn + (size_t)se * N_EMBED + kc + sk;
#pragma unroll
        for (int i = 0; i < 2; ++i) {
            const float4 a = *reinterpret_cast<const float4*>(wlp + 4 * i);
            const float4 b = *reinterpret_cast<const float4*>(wnp + 4 * i);
            Wt[sk + 4 * i + 0][se] = (double)a.x + (double)b.x;
            Wt[sk + 4 * i + 1][se] = (double)a.y + (double)b.y;
            Wt[sk + 4 * i + 2][se] = (double)a.z + (double)b.z;
            Wt[sk + 4 * i + 3][se] = (double)a.w + (double)b.w;
        }
        {
            const float* xp = x + (size_t)(t0 + st) * N_EMBED + kc + sx;
            const float4 a = *reinterpret_cast<const float4*>(xp);
            xsd[st][sx + 0] = (double)a.x;
            xsd[st][sx + 1] = (double)a.y;
            xsd[st][sx + 2] = (double)a.z;
            xsd[st][sx + 3] = (double)a.w;
        }
        __syncthreads();
#pragma unroll 4
        for (int kk = 0; kk < 64; kk += 4) {
            const double w0 = Wt[kk + 0][lane];
            const double w1 = Wt[kk + 1][lane];
            const double w2 = Wt[kk + 2][lane];
            const double w3 = Wt[kk + 3][lane];
#pragma unroll
            for (int t = 0; t < 4; ++t) {
                const double2 p = *reinterpret_cast<const double2*>(&xsd[tb + t][kk]);
                const double2 q = *reinterpret_cast<const double2*>(&xsd[tb + t][kk + 2]);
                acc[t] = fma(p.x, w0, acc[t]);
                acc[t] = fma(p.y, w1, acc[t]);
                acc[t] = fma(q.x, w2, acc[t]);
                acc[t] = fma(q.y, w3, acc[t]);
            }
        }
    }

    float* out_router = out;
    float* out_idx    = out + (size_t)n_tokens * N_EXPERTS;
#pragma unroll
    for (int t = 0; t < 4; ++t)
        topk8_write(acc[t] + myb, lane, (size_t)(t0 + tb + t), out_router, out_idx);
}

extern "C" void kernel_launch(void* const* d_in, const int* in_sizes, int n_in,
                              void* d_out, int out_size, void* d_ws, size_t ws_size,
                              hipStream_t stream) {
    const float* x  = (const float*)d_in[0];
    const float* Wl = (const float*)d_in[1];
    const float* bl = (const float*)d_in[2];
    const float* Wn = (const float*)d_in[3];
    const float* bn = (const float*)d_in[4];
    float* out = (float*)d_out;

    int n_tokens = in_sizes[0] / N_EMBED;              // 16384

    const size_t off_wgf   = (size_t)N_EXPERTS * N_EMBED * sizeof(double);   // 1 MB
    const size_t off_flags = off_wgf + (size_t)N_EXPERTS * N_EMBED * sizeof(float);
    const size_t off_part  = off_flags + (((size_t)n_tokens * 4 + 255) & ~255ull);
    const size_t need_full = off_part +
        (size_t)P1_KQ * n_tokens * N_EXPERTS * sizeof(float);                // +32 MB
    const size_t need_small = off_part;

    if (ws_size >= need_small) {
        double*   Wp    = (double*)d_ws;
        float*    Wgf   = (float*)((char*)d_ws + off_wgf);
        uint32_t* flags = (uint32_t*)((char*)d_ws + off_flags);

        hipLaunchKernelGGL(combine_w_kernel, dim3((N_EXPERTS * N_EMBED) / 256),
                           dim3(256), 0, stream, Wl, Wn, Wp, Wgf);

        if (ws_size >= need_full) {
            float* part = (float*)((char*)d_ws + off_part);
            hipLaunchKernelGGL(pass1a_kernel, dim3((n_tokens / 64) * P1_KQ),
                               dim3(512), 0, stream, x, Wgf, part, n_tokens);
            hipLaunchKernelGGL(pass1b_kernel, dim3(n_tokens / 64), dim3(1024),
                               0, stream, part, bl, bn, out, flags, n_tokens);
        } else {
            hipLaunchKernelGGL(pass1_full_kernel, dim3(n_tokens / 64), dim3(1024),
                               0, stream, x, Wgf, bl, bn, out, flags, n_tokens);
        }
        hipLaunchKernelGGL(pass2_kernel, dim3(n_tokens), dim3(256), 0, stream,
                           x, Wp, bl, bn, flags, out, n_tokens);
    } else {
        hipLaunchKernelGGL(noisy_topk_fallback, dim3(n_tokens / 32), dim3(512), 0, stream,
                           x, Wl, bl, Wn, bn, out, n_tokens);
    }
}

// Round 18
// 117.537 us; speedup vs baseline: 1.3713x; 1.0723x over previous
//
#include <hip/hip_runtime.h>
#include <math.h>
#include <stdint.h>

#define N_EMBED   2048
#define N_EXPERTS 64
#define TOP_K     8
#define THR       4e-4f         // 3x rigorous fp32 split-chain error bound
#define P1_KQ     4             // K split factor (pass 1a)
#define P1_KB     (N_EMBED / P1_KQ)   // 512 k per block
#define P1_KC     64            // k-chunk staged in LDS
#define P1_NCH    (P1_KB / P1_KC)     // 8
#define SLD       66            // x tile row stride (floats)

// ---------- fp64 monotone key (proven rounds 2-17) ----------
__device__ __forceinline__ uint64_t mono_key(double v, int lane) {
    uint64_t u = (uint64_t)__double_as_longlong(v);
    u = (u >> 63) ? ~u : (u | 0x8000000000000000ULL);
    return (u & ~63ULL) | (uint64_t)(63 - lane);
}
__device__ __forceinline__ double key_val(uint64_t k) {
    uint64_t u = k & ~63ULL;
    u = (u >> 63) ? (u & 0x7FFFFFFFFFFFFFFFULL) : ~u;
    return __longlong_as_double((long long)u);
}
// ---------- fp32 monotone key ----------
__device__ __forceinline__ uint32_t mono32(float v) {
    uint32_t u = __float_as_uint(v);
    return (u >> 31) ? ~u : (u | 0x80000000u);
}
__device__ __forceinline__ float val32(uint32_t k) {
    uint32_t u = (k & 0x80000000u) ? (k & 0x7FFFFFFFu) : ~k;
    return __uint_as_float(u);
}

// exact fp64 top-8 + softmax + store for one token (whole wave participates)
__device__ __forceinline__ void topk8_write(double v, int lane, size_t gtok,
                                            float* __restrict__ out_router,
                                            float* __restrict__ out_idx) {
    uint64_t mykey = mono_key(v, lane);
    float pv[TOP_K]; int pi[TOP_K];
    double vtop0 = 0.0;
#pragma unroll
    for (int j = 0; j < TOP_K; ++j) {
        uint64_t k = mykey;
#pragma unroll
        for (int m = 32; m >= 1; m >>= 1) {
            uint64_t o = (uint64_t)__shfl_xor((unsigned long long)k, m);
            k = (o > k) ? o : k;
        }
        const int widx = 63 - (int)(k & 63);
        const double wv = key_val(k);
        if (j == 0) vtop0 = wv;
        pv[j] = __expf((float)(wv - vtop0));
        pi[j] = widx;
        if (lane == widx) mykey = 0;
    }
    float s = 0.f;
#pragma unroll
    for (int j = 0; j < TOP_K; ++j) s += pv[j];
    const float inv = 1.f / s;

    float r = 0.f;
#pragma unroll
    for (int j = 0; j < TOP_K; ++j) r = (lane == pi[j]) ? pv[j] * inv : r;
    out_router[gtok * N_EXPERTS + lane] = r;

    float iv = 0.f;
#pragma unroll
    for (int j = 0; j < TOP_K; ++j) iv = (lane == j) ? (float)pi[j] : iv;
    if (lane < TOP_K)
        out_idx[gtok * TOP_K + lane] = iv;
}

// ---- prep: Wp fp64 k-major pairs (pass2) + Wg16 fp32 [e/16][k][16] (pass1a);
//      also zeroes the flagged-token counter ----
__global__ void combine_w_kernel(const float* __restrict__ Wl,
                                 const float* __restrict__ Wn,
                                 double* __restrict__ Wp,
                                 float* __restrict__ Wg16,
                                 uint32_t* __restrict__ count) {
    int f = blockIdx.x * 256 + threadIdx.x;    // = e*2048 + k, row-major
    if (f == 0) *count = 0;
    int k = f & (N_EMBED - 1);
    int e = f >> 11;
    double w = (double)Wl[f] + (double)Wn[f];
    Wp[(((size_t)(k >> 1) << 6) + e) * 2 + (k & 1)] = w;
    Wg16[(((size_t)(e >> 4) * N_EMBED + k) << 4) + (e & 15)] = (float)w;
}

// ---- pass 1a: fp32 GEMM partials. 1024 blocks = 256 tg x 4 kq.
//      512 thr = 8 waves = 4 expert-groups(16) x 2 k-halves; 4 blk/CU ----
__global__ __launch_bounds__(512, 8)
void pass1a_kernel(const float* __restrict__ x, const float* __restrict__ Wg16,
                   float* __restrict__ part, int n_tokens) {
    __shared__ float xsf[64 * SLD];        // 16,896 B; reused in epilogue

    const int tid  = threadIdx.x;
    const int lane = tid & 63;             // token
    const int wave = tid >> 6;             // 0..7
    const int tg   = blockIdx.x >> 2;
    const int kq   = blockIdx.x & 3;
    const int t0   = tg * 64;
    const int k0   = kq * P1_KB;

    const int wid = __builtin_amdgcn_readfirstlane(wave);
    const int eg  = wid & 3;               // experts [16eg, 16eg+16)
    const int kh  = wid >> 2;              // k-half of each chunk
    const int hb  = kh * 32;

    // staging: 8 threads per token, 8 consecutive k each
    const int stok = tid >> 3;
    const int sks  = (tid & 7) * 8;

    float accA[16], accB[16];
#pragma unroll
    for (int e = 0; e < 16; ++e) { accA[e] = 0.f; accB[e] = 0.f; }

    // prologue: prefetch chunk 0
    float4 pf0, pf1;
    {
        const float* xp = x + (size_t)(t0 + stok) * N_EMBED + k0 + sks;
        pf0 = *reinterpret_cast<const float4*>(xp);
        pf1 = *reinterpret_cast<const float4*>(xp + 4);
    }

    for (int c = 0; c < P1_NCH; ++c) {
        __syncthreads();               // previous chunk fully read

        // commit prefetched regs -> LDS
        {
            float* row = &xsf[stok * SLD + sks];
            float2 w0, w1, w2, w3;
            w0.x = pf0.x; w0.y = pf0.y; w1.x = pf0.z; w1.y = pf0.w;
            w2.x = pf1.x; w2.y = pf1.y; w3.x = pf1.z; w3.y = pf1.w;
            *reinterpret_cast<float2*>(row + 0) = w0;
            *reinterpret_cast<float2*>(row + 2) = w1;
            *reinterpret_cast<float2*>(row + 4) = w2;
            *reinterpret_cast<float2*>(row + 6) = w3;
        }
        __syncthreads();               // chunk staged

        // issue next chunk's loads (land during compute)
        if (c + 1 < P1_NCH) {
            const float* xp = x + (size_t)(t0 + stok) * N_EMBED + k0 + (c + 1) * P1_KC + sks;
            pf0 = *reinterpret_cast<const float4*>(xp);
            pf1 = *reinterpret_cast<const float4*>(xp + 4);
        }

        // compute: per 4k: 1 ds_read_b128 + 64 scalar W floats + 64 fma
        const float* wb = Wg16 + ((size_t)eg * N_EMBED + k0 + c * P1_KC + hb) * 16;
        const float* xr = &xsf[lane * SLD + hb];
#pragma unroll
        for (int i = 0; i < 8; ++i) {
            const float4 xv = *reinterpret_cast<const float4*>(xr + 4 * i);
            const float* w = wb + 64 * i;
#pragma unroll
            for (int e = 0; e < 16; ++e) accA[e] = fmaf(xv.x, w[e], accA[e]);
#pragma unroll
            for (int e = 0; e < 16; ++e) accA[e] = fmaf(xv.y, w[16 + e], accA[e]);
#pragma unroll
            for (int e = 0; e < 16; ++e) accB[e] = fmaf(xv.z, w[32 + e], accB[e]);
#pragma unroll
            for (int e = 0; e < 16; ++e) accB[e] = fmaf(xv.w, w[48 + e], accB[e]);
        }
    }
    __syncthreads();                   // x tile dead; reuse xsf

    // ---- combine k-halves, transpose, coalesced global write ----
    float* pbuf = xsf;                 // pbuf[(eg*64+t)*16 + e] : 4096 floats

    if (kh == 1) {
#pragma unroll
        for (int e = 0; e < 16; ++e)
            pbuf[(eg * 64 + lane) * 16 + e] = accA[e] + accB[e];
    }
    __syncthreads();

    float sum[16];
    if (kh == 0) {
#pragma unroll
        for (int e = 0; e < 16; ++e)
            sum[e] = (accA[e] + accB[e]) + pbuf[(eg * 64 + lane) * 16 + e];
    }
    __syncthreads();                   // pbuf read complete; reuse as nz

    float* nz = xsf;                   // nz[t*65 + e] : 4160 floats
    if (kh == 0) {
#pragma unroll
        for (int e = 0; e < 16; ++e)
            nz[lane * 65 + eg * 16 + e] = sum[e];
    }
    __syncthreads();

    {
        const int wt = tid >> 3;               // token 0..63
        const int wc = (tid & 7) * 8;          // expert col
        float4 v0, v1;
        v0.x = nz[wt * 65 + wc + 0];
        v0.y = nz[wt * 65 + wc + 1];
        v0.z = nz[wt * 65 + wc + 2];
        v0.w = nz[wt * 65 + wc + 3];
        v1.x = nz[wt * 65 + wc + 4];
        v1.y = nz[wt * 65 + wc + 5];
        v1.z = nz[wt * 65 + wc + 6];
        v1.w = nz[wt * 65 + wc + 7];
        float* dst = part + ((size_t)kq * n_tokens + t0 + wt) * N_EXPERTS + wc;
        *reinterpret_cast<float4*>(dst)     = v0;
        *reinterpret_cast<float4*>(dst + 4) = v1;
    }
}

// ---- pass 1b: sum 4 K-partials + bias, top-9 screen, compact flags, store ----
__global__ __launch_bounds__(1024, 1)
void pass1b_kernel(const float* __restrict__ part,
                   const float* __restrict__ bl, const float* __restrict__ bn,
                   float* __restrict__ out, uint32_t* __restrict__ count,
                   int* __restrict__ list, int n_tokens) {
    const int tid  = threadIdx.x;
    const int lane = tid & 63;             // expert
    const int wave = tid >> 6;             // 0..15
    const int t0   = blockIdx.x * 64;
    const int tb   = wave * 4;

    const float be = (float)((double)bl[lane] + (double)bn[lane]);
    float* out_router = out;
    float* out_idx    = out + (size_t)n_tokens * N_EXPERTS;

#pragma unroll
    for (int t = 0; t < 4; ++t) {
        const float* pb = part + (size_t)(t0 + tb + t) * N_EXPERTS + lane;
        float v = 0.f;
#pragma unroll
        for (int kq = 0; kq < P1_KQ; ++kq)
            v += pb[(size_t)kq * n_tokens * N_EXPERTS];
        v += be;

        uint32_t mykey = (mono32(v) & ~63u) | (uint32_t)(63 - lane);

        float pv[TOP_K]; int pi[TOP_K];
        float vtop = 0.f, vprev = 0.f, ming = 1e30f;
#pragma unroll
        for (int j = 0; j < 9; ++j) {
            uint32_t k = mykey;
#pragma unroll
            for (int m = 32; m >= 1; m >>= 1) {
                uint32_t o = (uint32_t)__shfl_xor((int)k, m);
                k = (o > k) ? o : k;
            }
            const int widx = 63 - (int)(k & 63);
            const float wv = val32(k);
            if (j == 0) vtop = wv;
            if (j > 0) ming = fminf(ming, vprev - wv);
            vprev = wv;
            if (j < TOP_K) {
                pv[j] = __expf(wv - vtop);
                pi[j] = widx;
                if (lane == widx) mykey = 0;            // remove winner
            }
        }
        float s = 0.f;
#pragma unroll
        for (int j = 0; j < TOP_K; ++j) s += pv[j];
        const float inv = 1.f / s;

        float r = 0.f;
#pragma unroll
        for (int j = 0; j < TOP_K; ++j) r = (lane == pi[j]) ? pv[j] * inv : r;
        out_router[(size_t)(t0 + tb + t) * N_EXPERTS + lane] = r;

        float iv = 0.f;
#pragma unroll
        for (int j = 0; j < TOP_K; ++j) iv = (lane == j) ? (float)pi[j] : iv;
        if (lane < TOP_K)
            out_idx[(size_t)(t0 + tb + t) * TOP_K + lane] = iv;

        if (lane == 0 && ming < THR) {
            const int idx = (int)atomicAdd(count, 1u);
            list[idx] = t0 + tb + t;
        }
    }
}

// ---- pass 2: exact fp64 repair over the COMPACTED flagged-token list ----
__global__ __launch_bounds__(256, 4)
void pass2_kernel(const float* __restrict__ x, const double* __restrict__ Wp,
                  const float* __restrict__ bl, const float* __restrict__ bn,
                  const uint32_t* __restrict__ count, const int* __restrict__ list,
                  float* __restrict__ out, int n_tokens) {
    __shared__ float  xls[N_EMBED];          // 8 KB x row
    __shared__ double dpart[4][N_EXPERTS];   // 2 KB partials

    const int tid  = threadIdx.x;
    const int lane = tid & 63;               // expert
    const int wave = tid >> 6;               // 0..3 (k-quarter)

    const int cnt = (int)*count;
    float* out_router = out;
    float* out_idx    = out + (size_t)n_tokens * N_EXPERTS;

    for (int i = blockIdx.x; i < cnt; i += gridDim.x) {
        const int t = list[i];

        // stage x row (coalesced, 8 floats/thread)
        {
            const float* xr = x + ((size_t)t << 11) + tid * 8;
            const float4 a = *reinterpret_cast<const float4*>(xr);
            const float4 b = *reinterpret_cast<const float4*>(xr + 4);
            *reinterpret_cast<float4*>(&xls[tid * 8])     = a;
            *reinterpret_cast<float4*>(&xls[tid * 8 + 4]) = b;
        }
        __syncthreads();

        // wave w owns k-pairs [256w, 256w+256); lane = expert, coalesced W
        double acc = 0.0;
        const double* wq = Wp + (((size_t)wave << 8) * 64 + lane) * 2;
#pragma unroll 4
        for (int q = 0; q < 256; ++q) {
            const float2  xf = *reinterpret_cast<const float2*>(&xls[(wave << 9) + 2 * q]);
            const double2 wp = *reinterpret_cast<const double2*>(wq + (size_t)q * 128);
            acc = fma((double)xf.x, wp.x, acc);
            acc = fma((double)xf.y, wp.y, acc);
        }
        dpart[wave][lane] = acc;
        __syncthreads();

        if (wave == 0) {
            const double myb = (double)bl[lane] + (double)bn[lane];
            double v = myb + dpart[0][lane] + dpart[1][lane]
                           + dpart[2][lane] + dpart[3][lane];
            topk8_write(v, lane, (size_t)t, out_router, out_idx);
        }
        __syncthreads();               // xls/dpart free for next token
    }
}

// ---- ultimate fallback: proven round-6 kernel (no workspace needed) ----
__global__ __launch_bounds__(512, 4)
void noisy_topk_fallback(const float* __restrict__ x,
                         const float* __restrict__ Wl, const float* __restrict__ bl,
                         const float* __restrict__ Wn, const float* __restrict__ bn,
                         float* __restrict__ out, int n_tokens) {
    __shared__ double Wt[64][N_EXPERTS];
    __shared__ double xsd[32][64];

    const int tid  = threadIdx.x;
    const int lane = tid & 63;
    const int wave = tid >> 6;
    const int t0   = blockIdx.x * 32;
    const int tb   = wave * 4;

    const int se = tid >> 3;
    const int sk = (tid & 7) * 8;
    const int st = tid >> 4;
    const int sx = (tid & 15) * 4;

    double acc[4];
#pragma unroll
    for (int t = 0; t < 4; ++t) acc[t] = 0.0;

    const double myb = (double)bl[lane] + (double)bn[lane];

    for (int c = 0; c < N_EMBED / 64; ++c) {
        const int kc = c * 64;
        __syncthreads();
        const float* wlp = Wl + (size_t)se * N_EMBED + kc + sk;
        const float* wnp = Wn + (size_t)se * N_EMBED + kc + sk;
#pragma unroll
        for (int i = 0; i < 2; ++i) {
            const float4 a = *reinterpret_cast<const float4*>(wlp + 4 * i);
            const float4 b = *reinterpret_cast<const float4*>(wnp + 4 * i);
            Wt[sk + 4 * i + 0][se] = (double)a.x + (double)b.x;
            Wt[sk + 4 * i + 1][se] = (double)a.y + (double)b.y;
            Wt[sk + 4 * i + 2][se] = (double)a.z + (double)b.z;
            Wt[sk + 4 * i + 3][se] = (double)a.w + (double)b.w;
        }
        {
            const float* xp = x + (size_t)(t0 + st) * N_EMBED + kc + sx;
            const float4 a = *reinterpret_cast<const float4*>(xp);
            xsd[st][sx + 0] = (double)a.x;
            xsd[st][sx + 1] = (double)a.y;
            xsd[st][sx + 2] = (double)a.z;
            xsd[st][sx + 3] = (double)a.w;
        }
        __syncthreads();
#pragma unroll 4
        for (int kk = 0; kk < 64; kk += 4) {
            const double w0 = Wt[kk + 0][lane];
            const double w1 = Wt[kk + 1][lane];
            const double w2 = Wt[kk + 2][lane];
            const double w3 = Wt[kk + 3][lane];
#pragma unroll
            for (int t = 0; t < 4; ++t) {
                const double2 p = *reinterpret_cast<const double2*>(&xsd[tb + t][kk]);
                const double2 q = *reinterpret_cast<const double2*>(&xsd[tb + t][kk + 2]);
                acc[t] = fma(p.x, w0, acc[t]);
                acc[t] = fma(p.y, w1, acc[t]);
                acc[t] = fma(q.x, w2, acc[t]);
                acc[t] = fma(q.y, w3, acc[t]);
            }
        }
    }

    float* out_router = out;
    float* out_idx    = out + (size_t)n_tokens * N_EXPERTS;
#pragma unroll
    for (int t = 0; t < 4; ++t)
        topk8_write(acc[t] + myb, lane, (size_t)(t0 + tb + t), out_router, out_idx);
}

extern "C" void kernel_launch(void* const* d_in, const int* in_sizes, int n_in,
                              void* d_out, int out_size, void* d_ws, size_t ws_size,
                              hipStream_t stream) {
    const float* x  = (const float*)d_in[0];
    const float* Wl = (const float*)d_in[1];
    const float* bl = (const float*)d_in[2];
    const float* Wn = (const float*)d_in[3];
    const float* bn = (const float*)d_in[4];
    float* out = (float*)d_out;

    int n_tokens = in_sizes[0] / N_EMBED;              // 16384

    const size_t off_wg16  = (size_t)N_EXPERTS * N_EMBED * sizeof(double);   // 1 MB
    const size_t off_count = off_wg16 + (size_t)N_EXPERTS * N_EMBED * sizeof(float);
    const size_t off_list  = off_count + 256;
    const size_t off_part  = (off_list + (size_t)n_tokens * sizeof(int) + 255) & ~255ull;
    const size_t need      = off_part +
        (size_t)P1_KQ * n_tokens * N_EXPERTS * sizeof(float);                // ~17.6 MB

    if (ws_size >= need) {
        double*   Wp    = (double*)d_ws;
        float*    Wg16  = (float*)((char*)d_ws + off_wg16);
        uint32_t* count = (uint32_t*)((char*)d_ws + off_count);
        int*      list  = (int*)((char*)d_ws + off_list);
        float*    part  = (float*)((char*)d_ws + off_part);

        hipLaunchKernelGGL(combine_w_kernel, dim3((N_EXPERTS * N_EMBED) / 256),
                           dim3(256), 0, stream, Wl, Wn, Wp, Wg16, count);
        hipLaunchKernelGGL(pass1a_kernel, dim3((n_tokens / 64) * P1_KQ),
                           dim3(512), 0, stream, x, Wg16, part, n_tokens);
        hipLaunchKernelGGL(pass1b_kernel, dim3(n_tokens / 64), dim3(1024),
                           0, stream, part, bl, bn, out, count, list, n_tokens);
        hipLaunchKernelGGL(pass2_kernel, dim3(1024), dim3(256), 0, stream,
                           x, Wp, bl, bn, count, list, out, n_tokens);
    } else {
        hipLaunchKernelGGL(noisy_topk_fallback, dim3(n_tokens / 32), dim3(512), 0, stream,
                           x, Wl, bl, Wn, bn, out, n_tokens);
    }
}

// Round 19
// 90.398 us; speedup vs baseline: 1.7830x; 1.3002x over previous
//
#include <hip/hip_runtime.h>
#include <math.h>
#include <stdint.h>

#define N_EMBED   2048
#define N_EXPERTS 64
#define TOP_K     8
#define THR       1.2e-3f       // 3x rigorous bf16-split screen error bound (~4e-4)

typedef short bf16x8 __attribute__((ext_vector_type(8)));
typedef float f32x16 __attribute__((ext_vector_type(16)));

// ---------- bf16 split helpers (RNE bit trick, finite data) ----------
__device__ __forceinline__ short f2bf(float f) {
    uint32_t u = __float_as_uint(f);
    u = u + 0x7fffu + ((u >> 16) & 1u);
    return (short)(u >> 16);
}
__device__ __forceinline__ float bf2f(short s) {
    return __uint_as_float(((uint32_t)(uint16_t)s) << 16);
}

// ---------- fp64 monotone key (proven rounds 2-18) ----------
__device__ __forceinline__ uint64_t mono_key(double v, int lane) {
    uint64_t u = (uint64_t)__double_as_longlong(v);
    u = (u >> 63) ? ~u : (u | 0x8000000000000000ULL);
    return (u & ~63ULL) | (uint64_t)(63 - lane);
}
__device__ __forceinline__ double key_val(uint64_t k) {
    uint64_t u = k & ~63ULL;
    u = (u >> 63) ? (u & 0x7FFFFFFFFFFFFFFFULL) : ~u;
    return __longlong_as_double((long long)u);
}
// ---------- fp32 monotone key ----------
__device__ __forceinline__ uint32_t mono32(float v) {
    uint32_t u = __float_as_uint(v);
    return (u >> 31) ? ~u : (u | 0x80000000u);
}
__device__ __forceinline__ float val32(uint32_t k) {
    uint32_t u = (k & 0x80000000u) ? (k & 0x7FFFFFFFu) : ~k;
    return __uint_as_float(u);
}

// exact fp64 top-8 + softmax + store for one token (whole wave participates)
__device__ __forceinline__ void topk8_write(double v, int lane, size_t gtok,
                                            float* __restrict__ out_router,
                                            float* __restrict__ out_idx) {
    uint64_t mykey = mono_key(v, lane);
    float pv[TOP_K]; int pi[TOP_K];
    double vtop0 = 0.0;
#pragma unroll
    for (int j = 0; j < TOP_K; ++j) {
        uint64_t k = mykey;
#pragma unroll
        for (int m = 32; m >= 1; m >>= 1) {
            uint64_t o = (uint64_t)__shfl_xor((unsigned long long)k, m);
            k = (o > k) ? o : k;
        }
        const int widx = 63 - (int)(k & 63);
        const double wv = key_val(k);
        if (j == 0) vtop0 = wv;
        pv[j] = __expf((float)(wv - vtop0));
        pi[j] = widx;
        if (lane == widx) mykey = 0;
    }
    float s = 0.f;
#pragma unroll
    for (int j = 0; j < TOP_K; ++j) s += pv[j];
    const float inv = 1.f / s;

    float r = 0.f;
#pragma unroll
    for (int j = 0; j < TOP_K; ++j) r = (lane == pi[j]) ? pv[j] * inv : r;
    out_router[gtok * N_EXPERTS + lane] = r;

    float iv = 0.f;
#pragma unroll
    for (int j = 0; j < TOP_K; ++j) iv = (lane == j) ? (float)pi[j] : iv;
    if (lane < TOP_K)
        out_idx[gtok * TOP_K + lane] = iv;
}

// ---- prep: Wp fp64 k-major pairs (pass2) + Whg/Wlg bf16 [e][k] (pass1);
//      zeroes the flagged-token counter ----
__global__ void combine_w_kernel(const float* __restrict__ Wl,
                                 const float* __restrict__ Wn,
                                 double* __restrict__ Wp,
                                 short* __restrict__ Whg,
                                 short* __restrict__ Wlg,
                                 uint32_t* __restrict__ count) {
    int f = blockIdx.x * 256 + threadIdx.x;    // = e*2048 + k, row-major
    if (f == 0) *count = 0;
    int k = f & (N_EMBED - 1);
    int e = f >> 11;
    double w = (double)Wl[f] + (double)Wn[f];
    Wp[(((size_t)(k >> 1) << 6) + e) * 2 + (k & 1)] = w;
    float w32 = (float)w;
    short wh = f2bf(w32);
    Whg[f] = wh;
    Wlg[f] = f2bf(w32 - bf2f(wh));
}

// ---- pass 1: bf16-split MFMA screen, fused top-9 + flag-list + stores.
//      256 blocks x 1024 thr; block = 64 tokens x 64 experts x K=2048.
//      16 waves = 2 tq x 2 eq x 4 kq; wave tile 32t x 32e. ----
#define KC    128
#define NCH   (N_EMBED / KC)
#define LDB   (KC + 8)          // bf16 row stride: 136 (16B-aligned rows)
#define XH    0
#define XL    (64 * LDB)
#define WH    (2 * 64 * LDB)
#define WLO   (3 * 64 * LDB)

__global__ __launch_bounds__(1024, 1)
void pass1_kernel(const float* __restrict__ x,
                  const short* __restrict__ Whg, const short* __restrict__ Wlg,
                  const float* __restrict__ bl, const float* __restrict__ bn,
                  float* __restrict__ out, uint32_t* __restrict__ count,
                  int* __restrict__ list, int n_tokens) {
    __shared__ short sbuf[4 * 64 * LDB];    // 69,632 B

    const int tid  = threadIdx.x;
    const int lane = tid & 63;
    const int wave = tid >> 6;              // 0..15
    const int t0   = blockIdx.x * 64;

    const int wid = __builtin_amdgcn_readfirstlane(wave);
    const int tq  = wid & 1;
    const int eq  = (wid >> 1) & 1;
    const int kq  = wid >> 2;               // 0..3: k-quarter of each chunk

    // staging ownership: 16 threads per row, 8 consecutive k each
    const int stok = tid >> 4;              // 0..63
    const int sks  = (tid & 15) * 8;        // 0..120

    f32x16 acc;
#pragma unroll
    for (int r = 0; r < 16; ++r) acc[r] = 0.f;

    // prologue: prefetch chunk 0 (x fp32, W bf16 h/l)
    float4 pf0, pf1;
    uint4  pwh, pwl;
    {
        const float* xp = x + (size_t)(t0 + stok) * N_EMBED + sks;
        pf0 = *reinterpret_cast<const float4*>(xp);
        pf1 = *reinterpret_cast<const float4*>(xp + 4);
        pwh = *reinterpret_cast<const uint4*>(&Whg[(size_t)stok * N_EMBED + sks]);
        pwl = *reinterpret_cast<const uint4*>(&Wlg[(size_t)stok * N_EMBED + sks]);
    }

    const int m  = lane & 31;
    const int g  = lane >> 5;
    const int ar = (tq * 32 + m) * LDB + 8 * g;   // A row base (x)
    const int br = (eq * 32 + m) * LDB + 8 * g;   // B row base (W), n = m

    for (int c = 0; c < NCH; ++c) {
        __syncthreads();               // previous chunk fully consumed

        // commit prefetched regs -> LDS (split x into bf16 hi/lo here)
        {
            float v[8] = {pf0.x, pf0.y, pf0.z, pf0.w, pf1.x, pf1.y, pf1.z, pf1.w};
            bf16x8 hv, lv;
#pragma unroll
            for (int i = 0; i < 8; ++i) {
                short h = f2bf(v[i]);
                hv[i] = h;
                lv[i] = f2bf(v[i] - bf2f(h));
            }
            *reinterpret_cast<bf16x8*>(&sbuf[XH + stok * LDB + sks]) = hv;
            *reinterpret_cast<bf16x8*>(&sbuf[XL + stok * LDB + sks]) = lv;
            *reinterpret_cast<uint4*>(&sbuf[WH + stok * LDB + sks])  = pwh;
            *reinterpret_cast<uint4*>(&sbuf[WLO + stok * LDB + sks]) = pwl;
        }
        __syncthreads();               // chunk staged

        // issue next chunk's global loads (land during compute)
        if (c + 1 < NCH) {
            const int kn = (c + 1) * KC;
            const float* xp = x + (size_t)(t0 + stok) * N_EMBED + kn + sks;
            pf0 = *reinterpret_cast<const float4*>(xp);
            pf1 = *reinterpret_cast<const float4*>(xp + 4);
            pwh = *reinterpret_cast<const uint4*>(&Whg[(size_t)stok * N_EMBED + kn + sks]);
            pwl = *reinterpret_cast<const uint4*>(&Wlg[(size_t)stok * N_EMBED + kn + sks]);
        }

        // compute: wave's k-quarter = 32k = 2 MFMA k-steps x 3 split terms
#pragma unroll
        for (int s = 0; s < 2; ++s) {
            const int kk = kq * 32 + s * 16;
            const bf16x8 ah = *reinterpret_cast<const bf16x8*>(&sbuf[XH + ar + kk]);
            const bf16x8 al = *reinterpret_cast<const bf16x8*>(&sbuf[XL + ar + kk]);
            const bf16x8 bh = *reinterpret_cast<const bf16x8*>(&sbuf[WH + br + kk]);
            const bf16x8 bw = *reinterpret_cast<const bf16x8*>(&sbuf[WLO + br + kk]);
            acc = __builtin_amdgcn_mfma_f32_32x32x16_bf16(ah, bh, acc, 0, 0, 0);
            acc = __builtin_amdgcn_mfma_f32_32x32x16_bf16(ah, bw, acc, 0, 0, 0);
            acc = __builtin_amdgcn_mfma_f32_32x32x16_bf16(al, bh, acc, 0, 0, 0);
        }
    }
    __syncthreads();                   // bf16 data dead; reuse sbuf as float

    // ---- combine 4 k-quarter partials per tile ----
    float* fb = reinterpret_cast<float*>(sbuf);   // 17,408 floats
    if (kq != 0) {
        const int idx = ((kq - 1) * 4 + tq * 2 + eq) * 64 + lane;
#pragma unroll
        for (int r = 0; r < 16; ++r) fb[idx * 17 + r] = acc[r];
    }
    __syncthreads();

    float* nzf = fb + 13056;                       // nz[64][66]
    if (kq == 0) {
        float accf[16];
#pragma unroll
        for (int r = 0; r < 16; ++r) accf[r] = acc[r];
#pragma unroll
        for (int j = 0; j < 3; ++j) {
            const int idx = (j * 4 + tq * 2 + eq) * 64 + lane;
#pragma unroll
            for (int r = 0; r < 16; ++r) accf[r] += fb[idx * 17 + r];
        }
        // D layout (verified m74/m101): col=lane&31, row=(r&3)+8*(r>>2)+4*(lane>>5)
        const int col = lane & 31;
        const int e = eq * 32 + col;
        const float be = (float)((double)bl[e] + (double)bn[e]);
#pragma unroll
        for (int r = 0; r < 16; ++r) {
            const int row = (r & 3) + 8 * (r >> 2) + 4 * (lane >> 5);
            nzf[(tq * 32 + row) * 66 + e] = accf[r] + be;
        }
    }
    __syncthreads();

    // ---- per-token top-9, margin flag (compact list), softmax, stores ----
    float* out_router = out;
    float* out_idx    = out + (size_t)n_tokens * N_EXPERTS;
    const int tb = wave * 4;

#pragma unroll
    for (int t = 0; t < 4; ++t) {
        const float v = nzf[(tb + t) * 66 + lane];      // lane = expert
        uint32_t mykey = (mono32(v) & ~63u) | (uint32_t)(63 - lane);

        float pv[TOP_K]; int pi[TOP_K];
        float vtop = 0.f, vprev = 0.f, ming = 1e30f;
#pragma unroll
        for (int j = 0; j < 9; ++j) {
            uint32_t k = mykey;
#pragma unroll
            for (int mm = 32; mm >= 1; mm >>= 1) {
                uint32_t o = (uint32_t)__shfl_xor((int)k, mm);
                k = (o > k) ? o : k;
            }
            const int widx = 63 - (int)(k & 63);
            const float wv = val32(k);
            if (j == 0) vtop = wv;
            if (j > 0) ming = fminf(ming, vprev - wv);
            vprev = wv;
            if (j < TOP_K) {
                pv[j] = __expf(wv - vtop);
                pi[j] = widx;
                if (lane == widx) mykey = 0;            // remove winner
            }
        }
        float s = 0.f;
#pragma unroll
        for (int j = 0; j < TOP_K; ++j) s += pv[j];
        const float inv = 1.f / s;

        float r = 0.f;
#pragma unroll
        for (int j = 0; j < TOP_K; ++j) r = (lane == pi[j]) ? pv[j] * inv : r;
        out_router[(size_t)(t0 + tb + t) * N_EXPERTS + lane] = r;

        float iv = 0.f;
#pragma unroll
        for (int j = 0; j < TOP_K; ++j) iv = (lane == j) ? (float)pi[j] : iv;
        if (lane < TOP_K)
            out_idx[(size_t)(t0 + tb + t) * TOP_K + lane] = iv;

        if (lane == 0 && ming < THR) {
            const int idx = (int)atomicAdd(count, 1u);
            list[idx] = t0 + tb + t;
        }
    }
}

// ---- pass 2: exact fp64 repair, 4 tokens per block (W stream amortized) ----
__global__ __launch_bounds__(256, 4)
void pass2_kernel(const float* __restrict__ x, const double* __restrict__ Wp,
                  const float* __restrict__ bl, const float* __restrict__ bn,
                  const uint32_t* __restrict__ count, const int* __restrict__ list,
                  float* __restrict__ out, int n_tokens) {
    __shared__ float  xls[4][N_EMBED];       // 32 KB
    __shared__ double dpart[4][4][64];       // 8 KB [tok][kq][e]

    const int tid  = threadIdx.x;
    const int lane = tid & 63;               // expert
    const int wave = tid >> 6;               // 0..3 (k-quarter / finisher token)

    const int cnt = (int)*count;
    float* out_router = out;
    float* out_idx    = out + (size_t)n_tokens * N_EXPERTS;
    const double myb = (double)bl[lane] + (double)bn[lane];

    for (int base = blockIdx.x * 4; base < cnt; base += gridDim.x * 4) {
        const int nval = min(4, cnt - base);

        // stage up to 4 x rows (coalesced)
#pragma unroll
        for (int j = 0; j < 4; ++j) {
            if (j < nval) {
                const int t = list[base + j];
                const float* xr = x + ((size_t)t << 11) + tid * 8;
                const float4 a = *reinterpret_cast<const float4*>(xr);
                const float4 b = *reinterpret_cast<const float4*>(xr + 4);
                *reinterpret_cast<float4*>(&xls[j][tid * 8])     = a;
                *reinterpret_cast<float4*>(&xls[j][tid * 8 + 4]) = b;
            }
        }
        __syncthreads();

        // wave = k-quarter; one W stream feeds all 4 tokens
        double a0 = 0.0, a1 = 0.0, a2 = 0.0, a3 = 0.0;
        const double* wq = Wp + (((size_t)wave << 8) * 64 + lane) * 2;
#pragma unroll 4
        for (int q = 0; q < 256; ++q) {
            const double2 wp = *reinterpret_cast<const double2*>(wq + (size_t)q * 128);
            const float2 x0 = *reinterpret_cast<const float2*>(&xls[0][(wave << 9) + 2 * q]);
            const float2 x1 = *reinterpret_cast<const float2*>(&xls[1][(wave << 9) + 2 * q]);
            const float2 x2 = *reinterpret_cast<const float2*>(&xls[2][(wave << 9) + 2 * q]);
            const float2 x3 = *reinterpret_cast<const float2*>(&xls[3][(wave << 9) + 2 * q]);
            a0 = fma((double)x0.x, wp.x, a0); a0 = fma((double)x0.y, wp.y, a0);
            a1 = fma((double)x1.x, wp.x, a1); a1 = fma((double)x1.y, wp.y, a1);
            a2 = fma((double)x2.x, wp.x, a2); a2 = fma((double)x2.y, wp.y, a2);
            a3 = fma((double)x3.x, wp.x, a3); a3 = fma((double)x3.y, wp.y, a3);
        }
        dpart[0][wave][lane] = a0;
        dpart[1][wave][lane] = a1;
        dpart[2][wave][lane] = a2;
        dpart[3][wave][lane] = a3;
        __syncthreads();

        if (wave < nval) {
            const int j = wave;
            const double v = myb + dpart[j][0][lane] + dpart[j][1][lane]
                                 + dpart[j][2][lane] + dpart[j][3][lane];
            topk8_write(v, lane, (size_t)list[base + j], out_router, out_idx);
        }
        __syncthreads();               // xls/dpart free for next group
    }
}

// ---- ultimate fallback: proven round-6 kernel (no workspace needed) ----
__global__ __launch_bounds__(512, 4)
void noisy_topk_fallback(const float* __restrict__ x,
                         const float* __restrict__ Wl, const float* __restrict__ bl,
                         const float* __restrict__ Wn, const float* __restrict__ bn,
                         float* __restrict__ out, int n_tokens) {
    __shared__ double Wt[64][N_EXPERTS];
    __shared__ double xsd[32][64];

    const int tid  = threadIdx.x;
    const int lane = tid & 63;
    const int wave = tid >> 6;
    const int t0   = blockIdx.x * 32;
    const int tb   = wave * 4;

    const int se = tid >> 3;
    const int sk = (tid & 7) * 8;
    const int st = tid >> 4;
    const int sx = (tid & 15) * 4;

    double acc[4];
#pragma unroll
    for (int t = 0; t < 4; ++t) acc[t] = 0.0;

    const double myb = (double)bl[lane] + (double)bn[lane];

    for (int c = 0; c < N_EMBED / 64; ++c) {
        const int kc = c * 64;
        __syncthreads();
        const float* wlp = Wl + (size_t)se * N_EMBED + kc + sk;
        const float* wnp = Wn + (size_t)se * N_EMBED + kc + sk;
#pragma unroll
        for (int i = 0; i < 2; ++i) {
            const float4 a = *reinterpret_cast<const float4*>(wlp + 4 * i);
            const float4 b = *reinterpret_cast<const float4*>(wnp + 4 * i);
            Wt[sk + 4 * i + 0][se] = (double)a.x + (double)b.x;
            Wt[sk + 4 * i + 1][se] = (double)a.y + (double)b.y;
            Wt[sk + 4 * i + 2][se] = (double)a.z + (double)b.z;
            Wt[sk + 4 * i + 3][se] = (double)a.w + (double)b.w;
        }
        {
            const float* xp = x + (size_t)(t0 + st) * N_EMBED + kc + sx;
            const float4 a = *reinterpret_cast<const float4*>(xp);
            xsd[st][sx + 0] = (double)a.x;
            xsd[st][sx + 1] = (double)a.y;
            xsd[st][sx + 2] = (double)a.z;
            xsd[st][sx + 3] = (double)a.w;
        }
        __syncthreads();
#pragma unroll 4
        for (int kk = 0; kk < 64; kk += 4) {
            const double w0 = Wt[kk + 0][lane];
            const double w1 = Wt[kk + 1][lane];
            const double w2 = Wt[kk + 2][lane];
            const double w3 = Wt[kk + 3][lane];
#pragma unroll
            for (int t = 0; t < 4; ++t) {
                const double2 p = *reinterpret_cast<const double2*>(&xsd[tb + t][kk]);
                const double2 q = *reinterpret_cast<const double2*>(&xsd[tb + t][kk + 2]);
                acc[t] = fma(p.x, w0, acc[t]);
                acc[t] = fma(p.y, w1, acc[t]);
                acc[t] = fma(q.x, w2, acc[t]);
                acc[t] = fma(q.y, w3, acc[t]);
            }
        }
    }

    float* out_router = out;
    float* out_idx    = out + (size_t)n_tokens * N_EXPERTS;
#pragma unroll
    for (int t = 0; t < 4; ++t)
        topk8_write(acc[t] + myb, lane, (size_t)(t0 + tb + t), out_router, out_idx);
}

extern "C" void kernel_launch(void* const* d_in, const int* in_sizes, int n_in,
                              void* d_out, int out_size, void* d_ws, size_t ws_size,
                              hipStream_t stream) {
    const float* x  = (const float*)d_in[0];
    const float* Wl = (const float*)d_in[1];
    const float* bl = (const float*)d_in[2];
    const float* Wn = (const float*)d_in[3];
    const float* bn = (const float*)d_in[4];
    float* out = (float*)d_out;

    int n_tokens = in_sizes[0] / N_EMBED;              // 16384

    const size_t off_wh    = (size_t)N_EXPERTS * N_EMBED * sizeof(double);   // 1 MB
    const size_t off_wlo   = off_wh + (size_t)N_EXPERTS * N_EMBED * sizeof(short);
    const size_t off_count = off_wlo + (size_t)N_EXPERTS * N_EMBED * sizeof(short);
    const size_t off_list  = off_count + 256;
    const size_t need      = off_list + (size_t)n_tokens * sizeof(int);      // ~1.6 MB

    if (ws_size >= need) {
        double*   Wp    = (double*)d_ws;
        short*    Whg   = (short*)((char*)d_ws + off_wh);
        short*    Wlg   = (short*)((char*)d_ws + off_wlo);
        uint32_t* count = (uint32_t*)((char*)d_ws + off_count);
        int*      list  = (int*)((char*)d_ws + off_list);

        hipLaunchKernelGGL(combine_w_kernel, dim3((N_EXPERTS * N_EMBED) / 256),
                           dim3(256), 0, stream, Wl, Wn, Wp, Whg, Wlg, count);
        hipLaunchKernelGGL(pass1_kernel, dim3(n_tokens / 64), dim3(1024), 0, stream,
                           x, Whg, Wlg, bl, bn, out, count, list, n_tokens);
        hipLaunchKernelGGL(pass2_kernel, dim3(512), dim3(256), 0, stream,
                           x, Wp, bl, bn, count, list, out, n_tokens);
    } else {
        hipLaunchKernelGGL(noisy_topk_fallback, dim3(n_tokens / 32), dim3(512), 0, stream,
                           x, Wl, bl, Wn, bn, out, n_tokens);
    }
}